// Round 9
// baseline (985.614 us; speedup 1.0000x reference)
//
#include <hip/hip_runtime.h>
#include <stdint.h>

// MultiClassDiceLoss: labels {1,2,3}, float32 vols with values in {0,1,2,3}.
// dice_l = 2*|A_l & B_l| / (|A_l| + |B_l| + eps); out = 1 - mean(dice_l).
// History (dice_count only; +~720us fixed harness poison fills in total):
//  R1 grid-stride float4 2-deep:  ~415 us (2.6 TB/s eff)
//  R3 block-linear+nt+8-deep:     ~324 us (3.3 TB/s eff)
//  R4-R7 pipeline/phase/front/u16: neutral or worse -> VGPR-return read path
//     service-rate wall at ~3.3 TB/s.
//  R8 global_load_lds DMA staging: ~245 us (4.4 TB/s) -- wall broken.
//  R9: R8 drains vmcnt to 0 every iter. Double-buffer LDS (2 x 1KiB per
//     volume per wave) + s_waitcnt vmcnt(2): in-flight DMAs oscillate 2-4,
//     never 0. Same LDS/block (16 KiB), same occupancy (8 blk/CU).

#define NCNT 9   // c1[1..3], c2[1..3], inter[1..3]
#define NBLK 2048
#define TPB  256

typedef unsigned int v4u __attribute__((ext_vector_type(4)));
typedef __attribute__((address_space(3))) uint8_t lds8_t;
typedef __attribute__((address_space(1))) const uint8_t glb8_t;

#define F1 0x3F800000u
#define F2 0x40000000u
#define F3 0x40400000u

__device__ __forceinline__ void count4u(v4u x, v4u y, unsigned int* c) {
#pragma unroll
    for (int comp = 0; comp < 4; ++comp) {
        const unsigned v = x[comp];
        const unsigned w = y[comp];
        bool a1 = (v == F1), a2 = (v == F2), a3 = (v == F3);
        bool b1 = (w == F1), b2 = (w == F2), b3 = (w == F3);
        c[0] += a1; c[1] += a2; c[2] += a3;
        c[3] += b1; c[4] += b2; c[5] += b3;
        c[6] += a1 & b1; c[7] += a2 & b2; c[8] += a3 & b3;
    }
}

__global__ __launch_bounds__(TPB, 8) void dice_count(const uint8_t* __restrict__ a,
                                                     const uint8_t* __restrict__ b,
                                                     unsigned int* __restrict__ partials,
                                                     long long n_bytes) {
    // per wave (4 KiB): [0,1K) A-buf0, [1K,2K) A-buf1, [2K,3K) B-buf0, [3K,4K) B-buf1
    __shared__ uint8_t smem[16384];

    unsigned int c[NCNT];
#pragma unroll
    for (int k = 0; k < NCNT; ++k) c[k] = 0u;

    const int w = threadIdx.x >> 6;      // wave id 0..3 (wave-uniform)
    const int l = threadIdx.x & 63;      // lane id

    const long long block_bytes = 4096;  // per volume per block-iteration
    const long long gstride = (long long)gridDim.x * block_bytes;  // 8 MiB
    const int iters = (int)(n_bytes / gstride);                    // 64

    // DMA dest: wave-uniform base (HW adds lane*16); global addr has lane off
    lds8_t* la[2] = { (lds8_t*)&smem[w * 4096],
                      (lds8_t*)&smem[w * 4096 + 1024] };
    lds8_t* lb[2] = { (lds8_t*)&smem[w * 4096 + 2048],
                      (lds8_t*)&smem[w * 4096 + 3072] };
    const v4u* ra[2] = { (const v4u*)&smem[w * 4096 + l * 16],
                         (const v4u*)&smem[w * 4096 + 1024 + l * 16] };
    const v4u* rb[2] = { (const v4u*)&smem[w * 4096 + 2048 + l * 16],
                         (const v4u*)&smem[w * 4096 + 3072 + l * 16] };

    const long long wave_off = (long long)blockIdx.x * block_bytes
                             + (long long)w * 1024 + (long long)l * 16;

    if (iters > 0) {
        // prologue: buffer 0 <- iteration 0
        __builtin_amdgcn_global_load_lds((glb8_t*)(a + wave_off), la[0], 16, 0, 0);
        __builtin_amdgcn_global_load_lds((glb8_t*)(b + wave_off), lb[0], 16, 0, 0);

        for (int j = 0; j + 1 < iters; ++j) {
            const int cur = j & 1, nxt = cur ^ 1;
            const long long nbase = wave_off + (long long)(j + 1) * gstride;
            // issue next iteration's DMAs before waiting on current's
            __builtin_amdgcn_global_load_lds((glb8_t*)(a + nbase), la[nxt], 16, 0, 0);
            __builtin_amdgcn_global_load_lds((glb8_t*)(b + nbase), lb[nxt], 16, 0, 0);
            __builtin_amdgcn_sched_barrier(0);
            __builtin_amdgcn_s_waitcnt(0xF72);   // vmcnt(2): current pair landed
            __builtin_amdgcn_sched_barrier(0);
            count4u(ra[cur][0], rb[cur][0], c);
            __builtin_amdgcn_sched_barrier(0);
        }
        __builtin_amdgcn_s_waitcnt(0xF70);       // vmcnt(0): last pair landed
        __builtin_amdgcn_sched_barrier(0);
        count4u(ra[(iters - 1) & 1][0], rb[(iters - 1) & 1][0], c);
    }

    // tail (empty for 512^3 with 2048 blocks; kept for generality)
    {
        const long long done = (long long)iters * gstride;   // bytes
        const unsigned int* au = (const unsigned int*)a;
        const unsigned int* bu = (const unsigned int*)b;
        const long long n_elem = n_bytes >> 2;
        for (long long e = (done >> 2) + blockIdx.x * TPB + threadIdx.x;
             e < n_elem; e += (long long)gridDim.x * TPB) {
            const unsigned v = au[e];
            const unsigned ww = bu[e];
            bool a1 = (v == F1), a2 = (v == F2), a3 = (v == F3);
            bool b1 = (ww == F1), b2 = (ww == F2), b3 = (ww == F3);
            c[0] += a1; c[1] += a2; c[2] += a3;
            c[3] += b1; c[4] += b2; c[5] += b3;
            c[6] += a1 & b1; c[7] += a2 & b2; c[8] += a3 & b3;
        }
    }

    // wave-level reduction (64 lanes)
#pragma unroll
    for (int k = 0; k < NCNT; ++k) {
#pragma unroll
        for (int off = 32; off > 0; off >>= 1)
            c[k] += __shfl_down(c[k], off, 64);
    }

    // cross-wave reduction: reuse staging LDS (all waves past their loops)
    __syncthreads();
    unsigned int* s = (unsigned int*)smem;   // [4][NCNT]
    if (l == 0) {
#pragma unroll
        for (int k = 0; k < NCNT; ++k) s[w * NCNT + k] = c[k];
    }
    __syncthreads();
    if (threadIdx.x == 0) {
#pragma unroll
        for (int k = 0; k < NCNT; ++k) {
            partials[blockIdx.x * NCNT + k] =
                s[0 * NCNT + k] + s[1 * NCNT + k] + s[2 * NCNT + k] + s[3 * NCNT + k];
        }
    }
}

__global__ __launch_bounds__(TPB) void dice_finalize(const unsigned int* __restrict__ partials,
                                                     float* __restrict__ out, int nblk) {
    unsigned int c[NCNT];
#pragma unroll
    for (int k = 0; k < NCNT; ++k) c[k] = 0u;
    for (int bidx = threadIdx.x; bidx < nblk; bidx += TPB) {
#pragma unroll
        for (int k = 0; k < NCNT; ++k) c[k] += partials[bidx * NCNT + k];
    }
#pragma unroll
    for (int k = 0; k < NCNT; ++k) {
#pragma unroll
        for (int off = 32; off > 0; off >>= 1)
            c[k] += __shfl_down(c[k], off, 64);
    }
    __shared__ unsigned int s[4][NCNT];
    const int w = threadIdx.x >> 6;
    const int l = threadIdx.x & 63;
    if (l == 0) {
#pragma unroll
        for (int k = 0; k < NCNT; ++k) s[w][k] = c[k];
    }
    __syncthreads();
    if (threadIdx.x == 0) {
        const double eps = 1.1920928955078125e-07;  // np.float32 eps
        double acc = 0.0;
#pragma unroll
        for (int lab = 0; lab < 3; ++lab) {
            double c1 = (double)(s[0][lab] + s[1][lab] + s[2][lab] + s[3][lab]);
            double c2 = (double)(s[0][3 + lab] + s[1][3 + lab] + s[2][3 + lab] + s[3][3 + lab]);
            double in = (double)(s[0][6 + lab] + s[1][6 + lab] + s[2][6 + lab] + s[3][6 + lab]);
            acc += (2.0 * in) / (c1 + c2 + eps);
        }
        out[0] = (float)(1.0 - acc / 3.0);
    }
}

extern "C" void kernel_launch(void* const* d_in, const int* in_sizes, int n_in,
                              void* d_out, int out_size, void* d_ws, size_t ws_size,
                              hipStream_t stream) {
    const uint8_t* v1 = (const uint8_t*)d_in[0];
    const uint8_t* v2 = (const uint8_t*)d_in[1];
    float* out = (float*)d_out;
    unsigned int* partials = (unsigned int*)d_ws;   // NBLK * NCNT u32

    const long long n_bytes = (long long)in_sizes[0] * 4;  // 512^3 floats

    dice_count<<<NBLK, TPB, 0, stream>>>(v1, v2, partials, n_bytes);
    dice_finalize<<<1, TPB, 0, stream>>>(partials, out, NBLK);
}

// Round 10
// 967.352 us; speedup vs baseline: 1.0189x; 1.0189x over previous
//
#include <hip/hip_runtime.h>
#include <stdint.h>

// MultiClassDiceLoss: labels {1,2,3}, float32 vols with values in {0,1,2,3}.
// dice_l = 2*|A_l & B_l| / (|A_l| + |B_l| + eps); out = 1 - mean(dice_l).
// History (dice_count only; total includes ~720us fixed harness poison fills):
//  R1 grid-stride float4 2-deep:   ~415 us (2.6 TB/s eff)
//  R3 block-linear+nt+8-deep:      ~324 us (3.3 TB/s)  VGPR-return path wall
//  R4-R7 pipeline/phase/front/u16: neutral or worse
//  R8 global_load_lds DMA staging: ~245 us (4.4 TB/s)  DMA path is faster
//  R9 double-buffer + vmcnt(2):    ~260 us REGRESSED -> intra-wave drain
//     discipline irrelevant (cross-wave overlap covers it); revert to R8.
//  R10: drive BOTH read paths at once. Per wave per iter: 1 KiB/volume via
//     DMA->LDS + 1 KiB/volume via nt VGPR loads, single vmcnt(0) drain,
//     consume both halves. If service queues are independent, rates add
//     (4.4 + 3.3 capped by ~6.5 fabric) -> ~170 us.

#define NCNT 9   // c1[1..3], c2[1..3], inter[1..3]
#define NBLK 2048
#define TPB  256

typedef unsigned int v4u __attribute__((ext_vector_type(4)));
typedef __attribute__((address_space(3))) uint8_t lds8_t;
typedef __attribute__((address_space(1))) const uint8_t glb8_t;

#define F1 0x3F800000u
#define F2 0x40000000u
#define F3 0x40400000u

__device__ __forceinline__ void count4u(v4u x, v4u y, unsigned int* c) {
#pragma unroll
    for (int comp = 0; comp < 4; ++comp) {
        const unsigned v = x[comp];
        const unsigned w = y[comp];
        bool a1 = (v == F1), a2 = (v == F2), a3 = (v == F3);
        bool b1 = (w == F1), b2 = (w == F2), b3 = (w == F3);
        c[0] += a1; c[1] += a2; c[2] += a3;
        c[3] += b1; c[4] += b2; c[5] += b3;
        c[6] += a1 & b1; c[7] += a2 & b2; c[8] += a3 & b3;
    }
}

__global__ __launch_bounds__(TPB, 8) void dice_count(const uint8_t* __restrict__ a,
                                                     const uint8_t* __restrict__ b,
                                                     unsigned int* __restrict__ partials,
                                                     long long n_bytes) {
    // A staging [0,4K): wave w at w*1024 ; B staging [4K,8K): 4096 + w*1024
    __shared__ uint8_t smem[8192];

    unsigned int c[NCNT];
#pragma unroll
    for (int k = 0; k < NCNT; ++k) c[k] = 0u;

    const int w = threadIdx.x >> 6;      // wave id 0..3 (wave-uniform)
    const int l = threadIdx.x & 63;      // lane id

    // per volume per block-iteration: 8 KiB (4 waves x 2 KiB: 1 DMA + 1 VGPR)
    const long long block_bytes = 8192;
    const long long gstride = (long long)gridDim.x * block_bytes;  // 16.78 MB
    const int iters = (int)(n_bytes / gstride);                    // 32

    lds8_t* la = (lds8_t*)&smem[w * 1024];
    lds8_t* lb = (lds8_t*)&smem[4096 + w * 1024];
    const v4u* ra = (const v4u*)&smem[w * 1024 + l * 16];
    const v4u* rb = (const v4u*)&smem[4096 + w * 1024 + l * 16];

    const long long wave_off = (long long)blockIdx.x * block_bytes
                             + (long long)w * 2048 + (long long)l * 16;

    for (int j = 0; j < iters; ++j) {
        const long long base = wave_off + (long long)j * gstride;
        // read path 1: DMA first KiB of this wave's 2 KiB span (per volume)
        __builtin_amdgcn_global_load_lds((glb8_t*)(a + base), la, 16, 0, 0);
        __builtin_amdgcn_global_load_lds((glb8_t*)(b + base), lb, 16, 0, 0);
        // read path 2: nt VGPR loads of the second KiB
        v4u xa = __builtin_nontemporal_load((const v4u*)(a + base + 1024));
        v4u yb = __builtin_nontemporal_load((const v4u*)(b + base + 1024));
        __builtin_amdgcn_sched_barrier(0);
        __builtin_amdgcn_s_waitcnt(0xF70);   // vmcnt(0): DMA + loads landed
        __builtin_amdgcn_sched_barrier(0);
        count4u(ra[0], rb[0], c);            // LDS half
        count4u(xa, yb, c);                  // register half
    }

    // tail (empty for 512^3 with 2048 blocks; kept for generality)
    {
        const long long done = (long long)iters * gstride;   // bytes
        const unsigned int* au = (const unsigned int*)a;
        const unsigned int* bu = (const unsigned int*)b;
        const long long n_elem = n_bytes >> 2;
        for (long long e = (done >> 2) + blockIdx.x * TPB + threadIdx.x;
             e < n_elem; e += (long long)gridDim.x * TPB) {
            const unsigned v = au[e];
            const unsigned ww = bu[e];
            bool a1 = (v == F1), a2 = (v == F2), a3 = (v == F3);
            bool b1 = (ww == F1), b2 = (ww == F2), b3 = (ww == F3);
            c[0] += a1; c[1] += a2; c[2] += a3;
            c[3] += b1; c[4] += b2; c[5] += b3;
            c[6] += a1 & b1; c[7] += a2 & b2; c[8] += a3 & b3;
        }
    }

    // wave-level reduction (64 lanes)
#pragma unroll
    for (int k = 0; k < NCNT; ++k) {
#pragma unroll
        for (int off = 32; off > 0; off >>= 1)
            c[k] += __shfl_down(c[k], off, 64);
    }

    // cross-wave reduction: reuse staging LDS (all waves past their loops)
    __syncthreads();
    unsigned int* s = (unsigned int*)smem;   // [4][NCNT]
    if (l == 0) {
#pragma unroll
        for (int k = 0; k < NCNT; ++k) s[w * NCNT + k] = c[k];
    }
    __syncthreads();
    if (threadIdx.x == 0) {
#pragma unroll
        for (int k = 0; k < NCNT; ++k) {
            partials[blockIdx.x * NCNT + k] =
                s[0 * NCNT + k] + s[1 * NCNT + k] + s[2 * NCNT + k] + s[3 * NCNT + k];
        }
    }
}

__global__ __launch_bounds__(TPB) void dice_finalize(const unsigned int* __restrict__ partials,
                                                     float* __restrict__ out, int nblk) {
    unsigned int c[NCNT];
#pragma unroll
    for (int k = 0; k < NCNT; ++k) c[k] = 0u;
    for (int bidx = threadIdx.x; bidx < nblk; bidx += TPB) {
#pragma unroll
        for (int k = 0; k < NCNT; ++k) c[k] += partials[bidx * NCNT + k];
    }
#pragma unroll
    for (int k = 0; k < NCNT; ++k) {
#pragma unroll
        for (int off = 32; off > 0; off >>= 1)
            c[k] += __shfl_down(c[k], off, 64);
    }
    __shared__ unsigned int s[4][NCNT];
    const int w = threadIdx.x >> 6;
    const int l = threadIdx.x & 63;
    if (l == 0) {
#pragma unroll
        for (int k = 0; k < NCNT; ++k) s[w][k] = c[k];
    }
    __syncthreads();
    if (threadIdx.x == 0) {
        const double eps = 1.1920928955078125e-07;  // np.float32 eps
        double acc = 0.0;
#pragma unroll
        for (int lab = 0; lab < 3; ++lab) {
            double c1 = (double)(s[0][lab] + s[1][lab] + s[2][lab] + s[3][lab]);
            double c2 = (double)(s[0][3 + lab] + s[1][3 + lab] + s[2][3 + lab] + s[3][3 + lab]);
            double in = (double)(s[0][6 + lab] + s[1][6 + lab] + s[2][6 + lab] + s[3][6 + lab]);
            acc += (2.0 * in) / (c1 + c2 + eps);
        }
        out[0] = (float)(1.0 - acc / 3.0);
    }
}

extern "C" void kernel_launch(void* const* d_in, const int* in_sizes, int n_in,
                              void* d_out, int out_size, void* d_ws, size_t ws_size,
                              hipStream_t stream) {
    const uint8_t* v1 = (const uint8_t*)d_in[0];
    const uint8_t* v2 = (const uint8_t*)d_in[1];
    float* out = (float*)d_out;
    unsigned int* partials = (unsigned int*)d_ws;   // NBLK * NCNT u32

    const long long n_bytes = (long long)in_sizes[0] * 4;  // 512^3 floats

    dice_count<<<NBLK, TPB, 0, stream>>>(v1, v2, partials, n_bytes);
    dice_finalize<<<1, TPB, 0, stream>>>(partials, out, NBLK);
}